// Round 9
// baseline (53.381 us; speedup 1.0000x reference)
//
#include <hip/hip_runtime.h>
#include <hip/hip_fp16.h>

#define NSUB 16
#define MM 20
#define NFILT 2000
#define TRI (MM*(MM+1)/2)
#define GR 250           // rows per block for both heavy kernels / G group size

// params published by setup kernel, consumed by later kernels (same-stream order)
__device__ __align__(16) float g_mu[32];
__device__ __align__(16) float g_W[16];
__device__ __align__(16) float g_Th[16];
__device__ float g_Vo;

__device__ __forceinline__ float ftanh(float x) {
  x = fminf(10.f, fmaxf(-10.f, x));
  float e = __expf(2.f * x);
  return (e - 1.f) * __builtin_amdgcn_rcpf(e + 1.f);
}

__device__ __forceinline__ float rfl(float v) {
  return __int_as_float(__builtin_amdgcn_readfirstlane(__float_as_int(v)));
}

__device__ __forceinline__ float f4c(const float4& v, int c) {
  return c == 0 ? v.x : c == 1 ? v.y : c == 2 ? v.z : v.w;
}

// full wave64 inclusive add-scan, pure VALU DPP (HW-validated R2)
__device__ __forceinline__ float wave_incl_scan(float x) {
  float t;
  t = __int_as_float(__builtin_amdgcn_update_dpp(0, __float_as_int(x), 0x111, 0xf, 0xf, true)); x += t;
  t = __int_as_float(__builtin_amdgcn_update_dpp(0, __float_as_int(x), 0x112, 0xf, 0xf, true)); x += t;
  t = __int_as_float(__builtin_amdgcn_update_dpp(0, __float_as_int(x), 0x114, 0xf, 0xf, true)); x += t;
  t = __int_as_float(__builtin_amdgcn_update_dpp(0, __float_as_int(x), 0x118, 0xf, 0xf, true)); x += t;
  t = __int_as_float(__builtin_amdgcn_update_dpp(0, __float_as_int(x), 0x142, 0xa, 0xf, true)); x += t; // bcast15
  t = __int_as_float(__builtin_amdgcn_update_dpp(0, __float_as_int(x), 0x143, 0xc, 0xf, true)); x += t; // bcast31
  return x;
}

// f16x2 helpers
__device__ __forceinline__ unsigned int f2h2(float a, float b) {
  __half2 h = __floats2half2_rn(a, b);
  union { __half2 h; unsigned int u; } cv; cv.h = h; return cv.u;
}
__device__ __forceinline__ void sub2(unsigned int cu, unsigned int lg, float& o0, float& o1) {
  union { unsigned int u; __half2 h; } a, b;
  a.u = cu; b.u = lg;
  float2 fa = __half22float2(a.h), fb = __half22float2(b.h);
  o0 = fa.x - fb.x; o1 = fa.y - fb.y;
}

// ---------------------------------------------------------------------------
// Setup: one 64-thread block per subunit; register-column Gauss-Jordan.
// (Validated R5-R8.)
// ---------------------------------------------------------------------------
__global__ void __launch_bounds__(64)
k_setup(const float* alpha_log, const float* beta_p, const float* gamma_log,
        const float* kvlog, const float* mean_u, const float* su_low,
        const float* u_in, const float* W_log, const float* V_o_p,
        const float* Theta, float* out, int T)
{
  const int s = blockIdx.x;       // 0..31
  const int lane = threadIdx.x;   // 0..63

  const float alpha = __expf(alpha_log[s]);
  const float beta  = beta_p[s];
  const float gamma = __expf(gamma_log[s]);
  const float kv    = __expf(kvlog[s]);
  const float fs    = (float)s;

  const long long OFF_MEANU = T;
  const long long OFF_SU    = (long long)T + 640;
  const long long OFF_COV   = (long long)T + 640 + 12800;
  const long long OFF_INV   = (long long)T + 640 + 2*12800;
  const long long OFF_FE    = (long long)T + 640 + 3*12800;
  const long long OFF_FI    = OFF_FE + 32000;
  const long long OFF_UIN   = OFF_FI + 32000;

  float urv[MM], t1v[MM], rv_[MM];
#pragma unroll
  for (int i = 0; i < MM; ++i) {
    float u = u_in[s*MM + i];
    urv[i] = u;
    t1v[i] = alpha * (u - beta) * (u - beta);
    rv_[i] = kv * __expf(-alpha*(fs-beta)*(fs-beta) - gamma*(fs-u)*(fs-u) - t1v[i]);
  }

  const bool cL = lane < MM;
  const bool cR = lane >= MM && lane < 2*MM;
  const float u_l = u_in[s*MM + (cL ? lane : 0)];
  const float t1_l = alpha * (u_l - beta) * (u_l - beta);

  float col[MM];
#pragma unroll
  for (int i = 0; i < MM; ++i) {
    float du = urv[i] - u_l;
    float cv = kv * __expf(-t1v[i] - gamma*du*du - t1_l);
    float idv = (lane - MM == i) ? 1.f : 0.f;
    col[i] = cL ? cv : (cR ? idv : 0.f);
    if (cL) out[OFF_COV + (long long)s*400 + i*MM + lane] = cv;
  }

#pragma unroll
  for (int k = 0; k < MM; ++k) {
    float fc[MM];
#pragma unroll
    for (int i = 0; i < MM; ++i)
      fc[i] = __int_as_float(__builtin_amdgcn_readlane(__float_as_int(col[i]), k));
    const float pr = 1.0f / fc[k];
    col[k] *= pr;
#pragma unroll
    for (int i = 0; i < MM; ++i)
      if (i != k) col[i] = fmaf(-fc[i], col[k], col[i]);
  }

  if (cR) {
    const int t = lane - MM;
#pragma unroll
    for (int i = 0; i < MM; ++i)
      out[OFF_INV + (long long)s*400 + i*MM + t] = col[i];
  }

  float dotr = 0.f;
#pragma unroll
  for (int i = 0; i < MM; ++i) dotr += rv_[i] * col[i];
  float mpart = cR ? dotr * mean_u[s*MM + (lane - MM)] : 0.f;
  float mu = mpart;
#pragma unroll
  for (int o = 1; o < 64; o <<= 1) mu += __shfl_xor(mu, o, 64);
  mu = rfl(mu);
  if (lane == 0) g_mu[s] = mu;

  __shared__ float Lm[MM][MM];
  for (int c = lane; c < MM*MM; c += 64) Lm[c/MM][c%MM] = 0.f;
  __syncthreads();
  for (int k = lane; k < TRI; k += 64) {
    int i = (int)((sqrtf(8.f*(float)k + 1.f) - 1.f) * 0.5f);
    while ((i+1)*(i+2)/2 <= k) ++i;
    while (i*(i+1)/2 > k) --i;
    int jx = k - i*(i+1)/2;
    Lm[i][jx] = su_low[s*TRI + k];
  }
  __syncthreads();
  for (int c = lane; c < MM*MM; c += 64) {
    int i = c / MM, kk = c % MM;
    float acc = 0.f;
#pragma unroll
    for (int jx = 0; jx < MM; ++jx) acc += Lm[i][jx] * Lm[kk][jx];
    out[OFF_SU + (long long)s*400 + c] = acc;
  }

  if (cL) {
    out[OFF_MEANU + s*MM + lane] = mean_u[s*MM + lane];
    out[OFF_UIN  + s*MM + lane] = u_l;
  }

  {
    long long base = (s < NSUB) ? (OFF_FE + (long long)s*NFILT)
                                : (OFF_FI + (long long)(s - NSUB)*NFILT);
    float2 f2 = make_float2(mu, mu);
    float2* dst = (float2*)(out + base);
    for (int n = lane; n < NFILT/2; n += 64) dst[n] = f2;
  }

  if (s == 0) {
    if (lane < 16) {
      g_W[lane]  = __expf(W_log[lane]);
      g_Th[lane] = Theta[lane];
    }
    if (lane == 0) g_Vo = V_o_p[0];
  }
}

// ---------------------------------------------------------------------------
// k_fold: pure stream, quarter-row per thread, 2000 blocks x 256 threads
// (8 blocks/CU via launch_bounds(256,8) -> 32 waves/CU). Block a covers rows
// [250a, 250a+250): 4 sweeps x 64 rows (last partially masked). All 8 loads
// issued up front. Dense float4 loads / uint2 stores. G[a][16] group sums.
// ---------------------------------------------------------------------------
__global__ void __launch_bounds__(256, 8)
k_fold(const float4* __restrict__ E4, const float4* __restrict__ I4,
       uint2* __restrict__ M2, float* __restrict__ G, int T)
{
  __shared__ float wsum[4][16];
  const int tid  = threadIdx.x;    // 0..255
  const int lane = tid & 63;
  const int w    = tid >> 6;       // 0..3
  const int g    = tid & 3;        // quarter: channels 4g..4g+3
  const int rq   = tid >> 2;       // 0..63 row-in-sweep
  const int a    = blockIdx.x;

  const float4 mue4 = *(const float4*)&g_mu[4*g];
  const float4 mui4 = *(const float4*)&g_mu[16 + 4*g];
  const float4 z4 = make_float4(0.f, 0.f, 0.f, 0.f);

  float gsum[4] = {0.f, 0.f, 0.f, 0.f};

  float4 ebuf[4], ibuf[4];
#pragma unroll
  for (int sw = 0; sw < 4; ++sw) {
    const int rl = sw*64 + rq;
    const long long r = (long long)a*GR + rl;
    const bool act = (rl < GR) && (r < T);
    const long long qi = r*4 + g;             // dense within wave
    ebuf[sw] = act ? E4[qi] : z4;
    ibuf[sw] = act ? I4[qi] : z4;
  }
#pragma unroll
  for (int sw = 0; sw < 4; ++sw) {
    const int rl = sw*64 + rq;
    const long long r = (long long)a*GR + rl;
    const bool act = (rl < GR) && (r < T);
    float m[4];
#pragma unroll
    for (int c = 0; c < 4; ++c) {
      m[c] = f4c(mue4, c)*f4c(ebuf[sw], c) + f4c(mui4, c)*f4c(ibuf[sw], c);
      gsum[c] += m[c];
    }
    if (act) {
      uint2 pk;
      pk.x = f2h2(m[0], m[1]);
      pk.y = f2h2(m[2], m[3]);
      M2[r*4 + g] = pk;                       // dense uint2 store
    }
  }

  // reduce group sums across lanes sharing this quarter
#pragma unroll
  for (int c = 0; c < 4; ++c) {
#pragma unroll
    for (int o = 4; o <= 32; o <<= 1) gsum[c] += __shfl_xor(gsum[c], o, 64);
  }
  if (lane < 4)
    *(float4*)&wsum[w][4*lane] = make_float4(gsum[0], gsum[1], gsum[2], gsum[3]);
  __syncthreads();
  if (tid < 16) {
    float acc = 0.f;
#pragma unroll
    for (int wp = 0; wp < 4; ++wp) acc += wsum[wp][tid];
    G[a*16 + tid] = acc;
  }
}

// ---------------------------------------------------------------------------
// k_out: 2000 blocks x 256 threads, 1 row/thread, rows [250b, 250b+250).
// W[t] = Th + sum(G over groups [b-8, b)) + scan(M[s..t] - M[s-2000..t-2000]).
// 4 uint4 loads/thread, DPP wave scan + 4x16 cross-wave LDS table,
// one tanh chain/thread, dense f32 store.
// ---------------------------------------------------------------------------
__global__ void __launch_bounds__(256, 4)
k_out(const uint4* __restrict__ M4, const float* __restrict__ G,
      float* __restrict__ out, int T)
{
  __shared__ float wdTot[4][16];
  __shared__ float bs0[16];
  const int tid  = threadIdx.x;    // 0..255
  const int lane = tid & 63;
  const int w    = tid >> 6;       // 0..3
  const int b    = blockIdx.x;
  const long long s = (long long)b * GR;
  const long long r = s + tid;
  const bool act = (tid < GR) && (r < T);
  const long long l = r - NFILT;
  const bool vl = act && (l >= 0);

  const uint4 zu = make_uint4(0u, 0u, 0u, 0u);
  uint4 c0 = act ? M4[r*2]     : zu;
  uint4 c1 = act ? M4[r*2 + 1] : zu;
  uint4 g0 = vl  ? M4[l*2]     : zu;
  uint4 g1 = vl  ? M4[l*2 + 1] : zu;

  // base from G: threads 0..15, one channel each
  if (tid < 16) {
    float acc = g_Th[tid];
#pragma unroll
    for (int gg = 0; gg < 8; ++gg) {
      const int gi = b - 8 + gg;
      if (gi >= 0) acc += G[gi*16 + tid];
    }
    bs0[tid] = acc;
  }

  float d[16];
  sub2(c0.x, g0.x, d[0],  d[1]);  sub2(c0.y, g0.y, d[2],  d[3]);
  sub2(c0.z, g0.z, d[4],  d[5]);  sub2(c0.w, g0.w, d[6],  d[7]);
  sub2(c1.x, g1.x, d[8],  d[9]);  sub2(c1.y, g1.y, d[10], d[11]);
  sub2(c1.z, g1.z, d[12], d[13]); sub2(c1.w, g1.w, d[14], d[15]);

  float inc[16];
#pragma unroll
  for (int c = 0; c < 16; ++c) {
    inc[c] = wave_incl_scan(d[c]);
    if (lane == 63) wdTot[w][c] = inc[c];
  }
  __syncthreads();

  // per-thread full base + chain input
  float Wv[16];
#pragma unroll
  for (int q = 0; q < 4; ++q) {
    float4 acc = *(const float4*)&bs0[4*q];
#pragma unroll
    for (int wp = 0; wp < 3; ++wp) {
      if (wp < w) {
        float4 dv = *(const float4*)&wdTot[wp][4*q];
        acc.x += dv.x; acc.y += dv.y; acc.z += dv.z; acc.w += dv.w;
      }
    }
    Wv[4*q]   = acc.x + inc[4*q];
    Wv[4*q+1] = acc.y + inc[4*q+1];
    Wv[4*q+2] = acc.z + inc[4*q+2];
    Wv[4*q+3] = acc.w + inc[4*q+3];
  }

  float wk[16];
#pragma unroll
  for (int k = 0; k < 16; ++k) wk[k] = rfl(g_W[k]);
  const float Vo = rfl(g_Vo);

  float v = ftanh(Wv[15]);
#pragma unroll
  for (int idx = 14; idx >= 0; --idx)
    v = ftanh(Wv[idx] + wk[idx + 1] * v);

  if (act) out[r] = v * wk[0] + Vo;
}

extern "C" void kernel_launch(void* const* d_in, const int* in_sizes, int n_in,
                              void* d_out, int out_size, void* d_ws, size_t ws_size,
                              hipStream_t stream) {
  const float* S_e       = (const float*)d_in[0];
  const float* S_i       = (const float*)d_in[1];
  const float* alpha_log = (const float*)d_in[2];
  const float* beta      = (const float*)d_in[3];
  const float* gamma_log = (const float*)d_in[4];
  const float* kvlog     = (const float*)d_in[5];
  const float* mean_u    = (const float*)d_in[6];
  const float* su_low    = (const float*)d_in[7];
  const float* u_in      = (const float*)d_in[8];
  const float* W_log     = (const float*)d_in[9];
  const float* V_o       = (const float*)d_in[10];
  const float* Theta     = (const float*)d_in[11];
  (void)n_in; (void)out_size; (void)ws_size;

  const int T = in_sizes[0] / NSUB;
  const int nG = (T + GR - 1) / GR;      // blocks for both heavy kernels

  // d_ws layout: M (f16, T x 16 ch = 32 B/row) then G (nG x 16 f32)
  uint2* M2 = (uint2*)d_ws;
  float* G  = (float*)((char*)d_ws + (size_t)T * 32);

  hipLaunchKernelGGL(k_setup, dim3(32), dim3(64), 0, stream,
                     alpha_log, beta, gamma_log, kvlog, mean_u, su_low, u_in,
                     W_log, V_o, Theta, (float*)d_out, T);
  hipLaunchKernelGGL(k_fold, dim3(nG), dim3(256), 0, stream,
                     (const float4*)S_e, (const float4*)S_i, M2, G, T);
  hipLaunchKernelGGL(k_out, dim3(nG), dim3(256), 0, stream,
                     (const uint4*)M2, G, (float*)d_out, T);
}